// Round 7
// baseline (251.832 us; speedup 1.0000x reference)
//
#include <hip/hip_runtime.h>
#include <hip/hip_bf16.h>

typedef __bf16 bf16;
typedef __attribute__((ext_vector_type(4))) __bf16 bf16x4;
typedef __attribute__((ext_vector_type(8))) __bf16 bf16x8;
typedef __attribute__((ext_vector_type(4))) float f32x4;

#define AS1C(p) ((const __attribute__((address_space(1))) void*)(p))
#define AS3(p)  ((__attribute__((address_space(3))) void*)(p))

static constexpr int B_ = 2, S_ = 2048, DM = 1024, H_ = 16, DK = 64;
static constexpr int M_ = B_ * S_;   // 4096 tokens
static constexpr int NW = DM * DM;   // 1M weight elems
static constexpr float QSCL = 0.125f * 1.44269504088896340736f;  // (1/sqrt dk)*log2(e)

__device__ __forceinline__ float fast_exp2(float x) {
#if __has_builtin(__builtin_amdgcn_exp2f)
  return __builtin_amdgcn_exp2f(x);
#else
  return exp2f(x);
#endif
}

// ---------------------------------------------------------------------------
// Weight casts fp32 -> bf16. cast_w3: Wq(scaled)/Wk/Wv via blockIdx.y.
// ---------------------------------------------------------------------------
__global__ __launch_bounds__(256) void cast_w3(
    const float* Wq, const float* Wk, const float* Wv, bf16* outw)
{
  const int z = blockIdx.y;
  const float* in = z == 0 ? Wq : (z == 1 ? Wk : Wv);
  const float s = z == 0 ? QSCL : 1.0f;
  bf16* out = outw + (size_t)z * NW;
  const int i = (blockIdx.x * 256 + threadIdx.x) * 8;
  f32x4 a = *(const f32x4*)(in + i);
  f32x4 b = *(const f32x4*)(in + i + 4);
  bf16x8 o;
#pragma unroll
  for (int j = 0; j < 4; ++j) { o[j] = (bf16)(a[j] * s); o[4 + j] = (bf16)(b[j] * s); }
  *(bf16x8*)(out + i) = o;
}

__global__ __launch_bounds__(256) void cast_f32_bf16(
    const float* __restrict__ in, bf16* __restrict__ out)
{
  const int i = (blockIdx.x * 256 + threadIdx.x) * 8;
  f32x4 a = *(const f32x4*)(in + i);
  f32x4 b = *(const f32x4*)(in + i + 4);
  bf16x8 o;
#pragma unroll
  for (int j = 0; j < 4; ++j) { o[j] = (bf16)a[j]; o[4 + j] = (bf16)b[j]; }
  *(bf16x8*)(out + i) = o;
}

// ---------------------------------------------------------------------------
// GEMM body: C[M,N] = A[M,K] @ W[N,K]^T + bias*bscale.  W bf16 (pre-cast).
// BK=64 as two BK=32 sub-tiles (pitch 64B keeps fragment reads 2-way free).
// A fp32 path: REGISTER-PREFETCHED (loads issue after barrier, land under
// MFMA phase; cvt+ds_write_b128 from regs). A bf16 path: global_load_lds.
// transv: write output transposed per-head as Vtg[b][h][d][tok].
// ---------------------------------------------------------------------------
template<int WTM, bool A_BF16, bool OUT_F32>
__device__ __forceinline__ void gemm_body(
    const void* __restrict__ Ain, const bf16* __restrict__ W,
    const float* __restrict__ bias, float bscale, void* __restrict__ Cout,
    bool transv, int M, int N, int K, int bx, int by)
{
  constexpr int BMt = 2 * WTM;
  constexpr int WI  = WTM / 16;
  __shared__ bf16 As[2 * BMt * 32];
  __shared__ bf16 Bs[2 * 128 * 32];

  const int tid  = threadIdx.x;
  const int wave = tid >> 6, lane = tid & 63;
  const int quad = lane >> 4, l16 = lane & 15;
  const int wm = wave >> 1, wn = wave & 1;
  const int row0 = by * BMt;
  const int col0 = bx * 128;

  const int srow  = lane >> 2;        // 0..15 (glds lane mapping)
  const int skcol = (lane & 3) * 8;   // 0,8,16,24

  // fp32-A prefetch mapping: thread -> (row, 16-k half)
  const int arow  = tid >> 1;               // 0..127 (BMt=128 case)
  const int ak16  = (tid & 1) * 16;         // 0 or 16 within a 32-k subtile
  const float* agp = nullptr;
  f32x4 pre[8];
  if constexpr (!A_BF16) {
    agp = (const float*)Ain + (size_t)(row0 + arow) * K + ak16;
#pragma unroll
    for (int hf = 0; hf < 2; ++hf)
#pragma unroll
      for (int c = 0; c < 4; ++c)
        pre[hf * 4 + c] = *(const f32x4*)(agp + hf * 32 + c * 4);
  }

  f32x4 acc[WI][4] = {};

  for (int k0 = 0; k0 < K; k0 += 64) {
    __syncthreads();                  // prev iter's LDS reads done
    if constexpr (A_BF16) {
      const bf16* A = (const bf16*)Ain;
#pragma unroll
      for (int hf = 0; hf < 2; ++hf)
#pragma unroll
        for (int c = wave; c < BMt / 16; c += 4)
          __builtin_amdgcn_global_load_lds(
              AS1C(A + (size_t)(row0 + c * 16 + srow) * K + k0 + hf * 32 + skcol),
              AS3(As + hf * BMt * 32 + c * 16 * 32), 16, 0, 0);
    } else {
      // write prefetched fp32 regs as bf16 into the two subtiles
#pragma unroll
      for (int hf = 0; hf < 2; ++hf) {
        bf16x8 w0, w1;
#pragma unroll
        for (int j = 0; j < 4; ++j) {
          w0[j]     = (bf16)pre[hf * 4 + 0][j];
          w0[4 + j] = (bf16)pre[hf * 4 + 1][j];
          w1[j]     = (bf16)pre[hf * 4 + 2][j];
          w1[4 + j] = (bf16)pre[hf * 4 + 3][j];
        }
        bf16* dst = As + hf * BMt * 32 + arow * 32 + ak16;
        *(bf16x8*)dst = w0;
        *(bf16x8*)(dst + 8) = w1;
      }
    }
#pragma unroll
    for (int hf = 0; hf < 2; ++hf)
#pragma unroll
      for (int i = 0; i < 2; ++i) {
        const int c = wave * 2 + i;
        __builtin_amdgcn_global_load_lds(
            AS1C(W + (size_t)(col0 + c * 16 + srow) * K + k0 + hf * 32 + skcol),
            AS3(Bs + hf * 128 * 32 + c * 16 * 32), 16, 0, 0);
      }
    __syncthreads();                  // staging ready (drains vmcnt)

    if constexpr (!A_BF16) {          // prefetch next tile (overlaps MFMA)
      if (k0 + 64 < K) {
#pragma unroll
        for (int hf = 0; hf < 2; ++hf)
#pragma unroll
          for (int c = 0; c < 4; ++c)
            pre[hf * 4 + c] = *(const f32x4*)(agp + k0 + 64 + hf * 32 + c * 4);
      }
    }

#pragma unroll
    for (int hf = 0; hf < 2; ++hf) {
      bf16x8 a[WI], bfr[4];
#pragma unroll
      for (int i = 0; i < WI; ++i)
        a[i] = *(const bf16x8*)(As + hf * BMt * 32 + (wm * WTM + i * 16 + l16) * 32 + quad * 8);
#pragma unroll
      for (int j = 0; j < 4; ++j)
        bfr[j] = *(const bf16x8*)(Bs + hf * 128 * 32 + (wn * 64 + j * 16 + l16) * 32 + quad * 8);
#pragma unroll
      for (int i = 0; i < WI; ++i)
#pragma unroll
        for (int j = 0; j < 4; ++j)
          acc[i][j] = __builtin_amdgcn_mfma_f32_16x16x32_bf16(a[i], bfr[j], acc[i][j], 0, 0, 0);
    }
  }

  // Epilogue: C/D layout col = lane&15, row = quad*4 + reg (m89-verified)
#pragma unroll
  for (int j = 0; j < 4; ++j) {
    const int col = col0 + wn * 64 + j * 16 + l16;
    const float bv = bias[col] * bscale;
    if (!OUT_F32 && transv) {
      const int hh = col >> 6, dd = col & 63;
#pragma unroll
      for (int i = 0; i < WI; ++i) {
        const int row = row0 + wm * WTM + i * 16 + quad * 4;  // 4 consecutive tokens
        const int bb2 = row >> 11, tok = row & 2047;
        bf16x4 o;
#pragma unroll
        for (int r = 0; r < 4; ++r) o[r] = (bf16)(acc[i][j][r] + bv);
        *(bf16x4*)((bf16*)Cout + (((size_t)bb2 * H_ + hh) * DK + dd) * S_ + tok) = o;
      }
    } else {
#pragma unroll
      for (int i = 0; i < WI; ++i) {
#pragma unroll
        for (int r = 0; r < 4; ++r) {
          const int row = row0 + wm * WTM + i * 16 + quad * 4 + r;
          const float val = acc[i][j][r] + bv;
          if constexpr (OUT_F32)
            ((float*)Cout)[(size_t)row * N + col] = val;
          else
            ((bf16*)Cout)[(size_t)row * N + col] = (bf16)val;
        }
      }
    }
  }
}

template<int WTM, bool A_BF16, bool OUT_F32>
__global__ __launch_bounds__(256) void gemm_bt(
    const void* __restrict__ Ain, const bf16* __restrict__ W,
    const float* __restrict__ bias, void* __restrict__ Cout,
    int M, int N, int K)
{
  gemm_body<WTM, A_BF16, OUT_F32>(Ain, W, bias, 1.0f, Cout, false, M, N, K,
                                  blockIdx.x, blockIdx.y);
}

// Fused Q/K/V projections, fp32 A straight from d_in (reg-prefetch path).
__global__ __launch_bounds__(256) void gemm_qkv(
    const float* A0, const float* A1, const float* A2,
    const bf16* __restrict__ Wc,
    const float* b0, const float* b1, const float* b2,
    bf16* C0, bf16* C1, bf16* C2, int M, int N, int K)
{
  const int z = blockIdx.z;
  const float* A = z == 0 ? A0 : (z == 1 ? A1 : A2);
  const float* bias = z == 0 ? b0 : (z == 1 ? b1 : b2);
  const float bscale = z == 0 ? QSCL : 1.0f;
  bf16* C = z == 0 ? C0 : (z == 1 ? C1 : C2);
  gemm_body<64, false, false>(A, Wc + (size_t)z * NW, bias, bscale, C,
                              z == 2, M, N, K, blockIdx.x, blockIdx.y);
}

// ---------------------------------------------------------------------------
// Flash attention, S^T/O^T, no online max; log2-domain scores (Wq pre-scaled).
// DOUBLE-BUFFERED K/V LDS: one barrier per KV tile; staging loads prefetched
// two tiles ahead in registers. V pre-transposed globally (Vtg[b][h][d][tok])
// so K and V staging are identical b128 row copies (pitch 72).
// Block = (b,h,64 q); 4 waves x 16 q; KV tile 64.
// ---------------------------------------------------------------------------
__global__ __launch_bounds__(256, 3) void attn_kernel(
    const bf16* __restrict__ Q, const bf16* __restrict__ Kb,
    const bf16* __restrict__ Vtg, bf16* __restrict__ O)
{
  __shared__ bf16 Kt[2][64 * 72];     // [buf][tok][d]
  __shared__ bf16 Vt[2][64 * 72];     // [buf][d][tok]
  __shared__ bf16 Ps[4 * 16 * 72];    // per-wave [q][tok]

  const int tid  = threadIdx.x;
  const int wave = tid >> 6, lane = tid & 63;
  const int quad = lane >> 4, l16 = lane & 15;
  const int b = blockIdx.z, h = blockIdx.y;
  const int q0 = blockIdx.x * 64 + wave * 16;
  const size_t base  = (size_t)b * S_ * DM + (size_t)h * DK;   // Q/K/O: [b][tok][h*64+d]
  const size_t baseV = ((size_t)b * H_ + h) * DK * S_;         // Vtg:   [b][h][d][tok]

  // Q frag [q=l16][k=quad*8+j] — pre-scaled by QSCL via the Wq cast
  bf16x8 qf[2];
#pragma unroll
  for (int kt = 0; kt < 2; ++kt)
    qf[kt] = *(const bf16x8*)(Q + base + (size_t)(q0 + l16) * DM + kt * 32 + quad * 8);

  // staging: waves 0-1 -> K rows (tok), waves 2-3 -> V^T rows (d). Mirrors.
  const bool kside = (wave < 2);
  const int srow  = kside ? (tid >> 1) : ((tid - 128) >> 1);   // 0..63
  const int shalf = tid & 1;
  const bf16* gp = kside
      ? (Kb + base + (size_t)srow * DM + shalf * 32)
      : (Vtg + baseV + (size_t)srow * S_ + shalf * 32);
  const size_t gstep = kside ? (size_t)64 * DM : 64;
  bf16* ldst0 = (kside ? Kt[0] : Vt[0]) + srow * 72 + shalf * 32;
  bf16* ldst1 = (kside ? Kt[1] : Vt[1]) + srow * 72 + shalf * 32;

  bf16x8 st[4];
#pragma unroll
  for (int c = 0; c < 4; ++c) st[c] = *(const bf16x8*)(gp + c * 8);
  // prologue: tile 0 -> buf 0 (no barrier needed; nothing has read it)
#pragma unroll
  for (int c = 0; c < 4; ++c) *(bf16x8*)(ldst0 + c * 8) = st[c];
  gp += gstep;
#pragma unroll
  for (int c = 0; c < 4; ++c) st[c] = *(const bf16x8*)(gp + c * 8);  // tile 1
  gp += gstep;

  f32x4 lacc = {0.f, 0.f, 0.f, 0.f};   // per-lane partial sums of exp
  f32x4 accO[4] = {};                  // O^T[d=dt*16+quad*4+r][q=l16]
  bf16* Pw = Ps + wave * 16 * 72;

  constexpr int NIT = S_ / 64;
  for (int it = 0; it < NIT; ++it) {
    const int bsel = it & 1;
    __syncthreads();   // buf[bsel] writes visible; prev reads of buf[bsel^1] done

    if (it + 1 < NIT) {                // write tile it+1 into the other buffer
      bf16* dst = bsel ? ldst0 : ldst1;
#pragma unroll
      for (int c = 0; c < 4; ++c) *(bf16x8*)(dst + c * 8) = st[c];
      if (it + 2 < NIT) {              // prefetch tile it+2
#pragma unroll
        for (int c = 0; c < 4; ++c) st[c] = *(const bf16x8*)(gp + c * 8);
        gp += gstep;
      }
    }

    const bf16* Kc = Kt[bsel];
    const bf16* Vc = Vt[bsel];

    // ---- S^T: 4 tiles [16 tok][16 q]; log2-domain scores ----
    f32x4 sc[4];
#pragma unroll
    for (int ct = 0; ct < 4; ++ct) {
      const bf16* kp = Kc + (ct * 16 + l16) * 72 + quad * 8;
      f32x4 a = {0.f, 0.f, 0.f, 0.f};
      a = __builtin_amdgcn_mfma_f32_16x16x32_bf16(*(const bf16x8*)kp,        qf[0], a, 0, 0, 0);
      a = __builtin_amdgcn_mfma_f32_16x16x32_bf16(*(const bf16x8*)(kp + 32), qf[1], a, 0, 0, 0);
      sc[ct] = a;
    }

    // ---- p = exp2(sc); 4 independent l-chains; P^T -> per-wave LDS ----
#pragma unroll
    for (int ct = 0; ct < 4; ++ct) {
      bf16x4 pk;
#pragma unroll
      for (int r = 0; r < 4; ++r) {
        const float p = fast_exp2(sc[ct][r]);
        lacc[r] += p;
        pk[r] = (bf16)p;
      }
      *(bf16x4*)(Pw + l16 * 72 + ct * 16 + quad * 4) = pk;
    }
    bf16x8 pf0 = *(const bf16x8*)(Pw + l16 * 72 + quad * 8);
    bf16x8 pf1 = *(const bf16x8*)(Pw + l16 * 72 + 32 + quad * 8);

    // ---- O^T += V^T P ----
#pragma unroll
    for (int dt = 0; dt < 4; ++dt) {
      const bf16* vp = Vc + (dt * 16 + l16) * 72;
      accO[dt] = __builtin_amdgcn_mfma_f32_16x16x32_bf16(
          *(const bf16x8*)(vp + quad * 8),      pf0, accO[dt], 0, 0, 0);
      accO[dt] = __builtin_amdgcn_mfma_f32_16x16x32_bf16(
          *(const bf16x8*)(vp + 32 + quad * 8), pf1, accO[dt], 0, 0, 0);
    }
  }

  // ---- epilogue: reduce l, O[q][d] = O^T / l (in-lane, q = l16) ----
  float l_s = (lacc[0] + lacc[1]) + (lacc[2] + lacc[3]);
  l_s += __shfl_xor(l_s, 16, 64);
  l_s += __shfl_xor(l_s, 32, 64);
  const float inv = 1.0f / l_s;
#pragma unroll
  for (int dt = 0; dt < 4; ++dt) {
    bf16x4 o;
#pragma unroll
    for (int r = 0; r < 4; ++r) o[r] = (bf16)(accO[dt][r] * inv);
    *(bf16x4*)(O + base + (size_t)(q0 + l16) * DM + dt * 16 + quad * 4) = o;
  }
}

// ---------------------------------------------------------------------------
extern "C" void kernel_launch(void* const* d_in, const int* in_sizes, int n_in,
                              void* d_out, int out_size, void* d_ws, size_t ws_size,
                              hipStream_t stream) {
  (void)in_sizes; (void)n_in; (void)out_size; (void)ws_size;
  const float* q  = (const float*)d_in[0];
  const float* k  = (const float*)d_in[1];
  const float* v  = (const float*)d_in[2];
  const float* Wq = (const float*)d_in[3];
  const float* bq = (const float*)d_in[4];
  const float* Wk = (const float*)d_in[5];
  const float* bk = (const float*)d_in[6];
  const float* Wv = (const float*)d_in[7];
  const float* bvv= (const float*)d_in[8];
  const float* Wo = (const float*)d_in[9];
  const float* bo = (const float*)d_in[10];
  float* out = (float*)d_out;

  // 32 MB workspace plan (ws >= 32 MB proven since R2):
  //  [ 0, 8)  Qb          [ 8,16)  Kbf  (-> Woc after attn)
  //  [16,24)  Vtg         [24,30)  Wqkv-cast (dead after QKV GEMM)
  //  [24,32)  Ab (attn out, overwrites Wqkv)
  char* ws = (char*)d_ws;
  const size_t MB = 1024 * 1024;
  bf16* Qb  = (bf16*)(ws);
  bf16* Kbf = (bf16*)(ws + 8 * MB);
  bf16* Vtg = (bf16*)(ws + 16 * MB);
  bf16* Wc  = (bf16*)(ws + 24 * MB);
  bf16* Ab  = (bf16*)(ws + 24 * MB);
  bf16* WoC = (bf16*)(ws + 8 * MB);   // overwrites dead Kbf post-attn

  dim3 bb(256, 1, 1);

  cast_w3<<<dim3(NW / 2048, 3, 1), bb, 0, stream>>>(Wq, Wk, Wv, Wc);

  gemm_qkv<<<dim3(DM / 128, M_ / 128, 3), bb, 0, stream>>>(
      q, k, v, Wc, bq, bk, bvv, Qb, Kbf, Vtg, M_, DM, DM);

  attn_kernel<<<dim3(S_ / 64, H_, B_), bb, 0, stream>>>(Qb, Kbf, Vtg, Ab);

  cast_f32_bf16<<<dim3(NW / 2048, 1, 1), bb, 0, stream>>>(Wo, WoC);

  gemm_bt<32, true, true><<<dim3(DM / 128, M_ / 64, 1), bb, 0, stream>>>(
      Ab, WoC, bo, out, M_, DM, DM);
}

// Round 8
// 223.225 us; speedup vs baseline: 1.1282x; 1.1282x over previous
//
#include <hip/hip_runtime.h>
#include <hip/hip_bf16.h>

typedef __bf16 bf16;
typedef __attribute__((ext_vector_type(4))) __bf16 bf16x4;
typedef __attribute__((ext_vector_type(8))) __bf16 bf16x8;
typedef __attribute__((ext_vector_type(4))) float f32x4;

#define AS1C(p) ((const __attribute__((address_space(1))) void*)(p))
#define AS3(p)  ((__attribute__((address_space(3))) void*)(p))

static constexpr int B_ = 2, S_ = 2048, DM = 1024, H_ = 16, DK = 64;
static constexpr int M_ = B_ * S_;   // 4096 tokens
static constexpr int NW = DM * DM;   // 1M weight elems
static constexpr float QSCL = 0.125f * 1.44269504088896340736f;  // (1/sqrt dk)*log2(e)

__device__ __forceinline__ float fast_exp2(float x) {
#if __has_builtin(__builtin_amdgcn_exp2f)
  return __builtin_amdgcn_exp2f(x);
#else
  return exp2f(x);
#endif
}

// ---------------------------------------------------------------------------
// All four weight casts fp32 -> bf16 in one launch. z=0..2 -> Wc[z], z=3 -> WoC.
// ---------------------------------------------------------------------------
__global__ __launch_bounds__(256) void cast_w4(
    const float* Wq, const float* Wk, const float* Wv, const float* Wo,
    bf16* Wc, bf16* WoC)
{
  const int z = blockIdx.y;
  const float* in = z == 0 ? Wq : (z == 1 ? Wk : (z == 2 ? Wv : Wo));
  const float s = z == 0 ? QSCL : 1.0f;
  bf16* out = z < 3 ? (Wc + (size_t)z * NW) : WoC;
  const int i = (blockIdx.x * 256 + threadIdx.x) * 8;
  f32x4 a = *(const f32x4*)(in + i);
  f32x4 b = *(const f32x4*)(in + i + 4);
  bf16x8 o;
#pragma unroll
  for (int j = 0; j < 4; ++j) { o[j] = (bf16)(a[j] * s); o[4 + j] = (bf16)(b[j] * s); }
  *(bf16x8*)(out + i) = o;
}

// ---------------------------------------------------------------------------
// GEMM body: C[M,N] = A[M,K] @ W[N,K]^T + bias*bscale.  W bf16 (pre-cast).
// BK=64 as two BK=32 sub-tiles. A fp32: register-prefetched, cvt+b128 from
// regs. A bf16: global_load_lds. transv: output as Vtg[b][h][d][tok].
// Callers pass XCD-swizzled (bx, by).
// ---------------------------------------------------------------------------
template<int WTM, bool A_BF16, bool OUT_F32>
__device__ __forceinline__ void gemm_body(
    const void* __restrict__ Ain, const bf16* __restrict__ W,
    const float* __restrict__ bias, float bscale, void* __restrict__ Cout,
    bool transv, int M, int N, int K, int bx, int by)
{
  constexpr int BMt = 2 * WTM;
  constexpr int WI  = WTM / 16;
  __shared__ bf16 As[2 * BMt * 32];
  __shared__ bf16 Bs[2 * 128 * 32];

  const int tid  = threadIdx.x;
  const int wave = tid >> 6, lane = tid & 63;
  const int quad = lane >> 4, l16 = lane & 15;
  const int wm = wave >> 1, wn = wave & 1;
  const int row0 = by * BMt;
  const int col0 = bx * 128;

  const int srow  = lane >> 2;        // glds lane mapping
  const int skcol = (lane & 3) * 8;

  // fp32-A prefetch mapping: thread -> (row, 16-k half)
  const int arow  = (tid >> 1) & (BMt - 1);
  const int ak16  = (tid & 1) * 16;
  const float* agp = nullptr;
  f32x4 pre[8];
  if constexpr (!A_BF16) {
    agp = (const float*)Ain + (size_t)(row0 + arow) * K + ak16;
#pragma unroll
    for (int hf = 0; hf < 2; ++hf)
#pragma unroll
      for (int c = 0; c < 4; ++c)
        pre[hf * 4 + c] = *(const f32x4*)(agp + hf * 32 + c * 4);
  }

  f32x4 acc[WI][4] = {};

  for (int k0 = 0; k0 < K; k0 += 64) {
    __syncthreads();                  // prev iter's LDS reads done
    if constexpr (A_BF16) {
      const bf16* A = (const bf16*)Ain;
#pragma unroll
      for (int hf = 0; hf < 2; ++hf)
#pragma unroll
        for (int c = wave; c < BMt / 16; c += 4)
          __builtin_amdgcn_global_load_lds(
              AS1C(A + (size_t)(row0 + c * 16 + srow) * K + k0 + hf * 32 + skcol),
              AS3(As + hf * BMt * 32 + c * 16 * 32), 16, 0, 0);
    } else {
#pragma unroll
      for (int hf = 0; hf < 2; ++hf) {
        bf16x8 w0, w1;
#pragma unroll
        for (int j = 0; j < 4; ++j) {
          w0[j]     = (bf16)pre[hf * 4 + 0][j];
          w0[4 + j] = (bf16)pre[hf * 4 + 1][j];
          w1[j]     = (bf16)pre[hf * 4 + 2][j];
          w1[4 + j] = (bf16)pre[hf * 4 + 3][j];
        }
        bf16* dst = As + hf * BMt * 32 + arow * 32 + ak16;
        *(bf16x8*)dst = w0;
        *(bf16x8*)(dst + 8) = w1;
      }
    }
#pragma unroll
    for (int hf = 0; hf < 2; ++hf)
#pragma unroll
      for (int i = 0; i < 2; ++i) {
        const int c = wave * 2 + i;
        __builtin_amdgcn_global_load_lds(
            AS1C(W + (size_t)(col0 + c * 16 + srow) * K + k0 + hf * 32 + skcol),
            AS3(Bs + hf * 128 * 32 + c * 16 * 32), 16, 0, 0);
      }
    __syncthreads();                  // staging ready (drains vmcnt)

    if constexpr (!A_BF16) {          // prefetch next tile (overlaps MFMA)
      if (k0 + 64 < K) {
#pragma unroll
        for (int hf = 0; hf < 2; ++hf)
#pragma unroll
          for (int c = 0; c < 4; ++c)
            pre[hf * 4 + c] = *(const f32x4*)(agp + k0 + 64 + hf * 32 + c * 4);
      }
    }

#pragma unroll
    for (int hf = 0; hf < 2; ++hf) {
      bf16x8 a[WI], bfr[4];
#pragma unroll
      for (int i = 0; i < WI; ++i)
        a[i] = *(const bf16x8*)(As + hf * BMt * 32 + (wm * WTM + i * 16 + l16) * 32 + quad * 8);
#pragma unroll
      for (int j = 0; j < 4; ++j)
        bfr[j] = *(const bf16x8*)(Bs + hf * 128 * 32 + (wn * 64 + j * 16 + l16) * 32 + quad * 8);
#pragma unroll
      for (int i = 0; i < WI; ++i)
#pragma unroll
        for (int j = 0; j < 4; ++j)
          acc[i][j] = __builtin_amdgcn_mfma_f32_16x16x32_bf16(a[i], bfr[j], acc[i][j], 0, 0, 0);
    }
  }

  // Epilogue: C/D layout col = lane&15, row = quad*4 + reg
#pragma unroll
  for (int j = 0; j < 4; ++j) {
    const int col = col0 + wn * 64 + j * 16 + l16;
    const float bv = bias[col] * bscale;
    if (!OUT_F32 && transv) {
      const int hh = col >> 6, dd = col & 63;
#pragma unroll
      for (int i = 0; i < WI; ++i) {
        const int row = row0 + wm * WTM + i * 16 + quad * 4;
        const int bb2 = row >> 11, tok = row & 2047;
        bf16x4 o;
#pragma unroll
        for (int r = 0; r < 4; ++r) o[r] = (bf16)(acc[i][j][r] + bv);
        *(bf16x4*)((bf16*)Cout + (((size_t)bb2 * H_ + hh) * DK + dd) * S_ + tok) = o;
      }
    } else {
#pragma unroll
      for (int i = 0; i < WI; ++i) {
#pragma unroll
        for (int r = 0; r < 4; ++r) {
          const int row = row0 + wm * WTM + i * 16 + quad * 4 + r;
          const float val = acc[i][j][r] + bv;
          if constexpr (OUT_F32)
            ((float*)Cout)[(size_t)row * N + col] = val;
          else
            ((bf16*)Cout)[(size_t)row * N + col] = (bf16)val;
        }
      }
    }
  }
}

// Fused Q/K/V projections, fp32 A from d_in. Flat grid (768) with XCD
// swizzle: blocks sharing an A row-strip get IDs differing by 32 (==0 mod 8)
// -> same XCD -> strip fetched once, re-reads served by that XCD's L2.
__global__ __launch_bounds__(256) void gemm_qkv(
    const float* A0, const float* A1, const float* A2,
    const bf16* __restrict__ Wc,
    const float* b0, const float* b1, const float* b2,
    bf16* C0, bf16* C1, bf16* C2, int M, int N, int K)
{
  const int id = blockIdx.x;
  const int z  = id >> 8;            // 0..2
  const int r  = id & 255;
  const int by = r & 31;             // same-by blocks: ids differ by 32
  const int bx = r >> 5;             // 0..7
  const float* A = z == 0 ? A0 : (z == 1 ? A1 : A2);
  const float* bias = z == 0 ? b0 : (z == 1 ? b1 : b2);
  const float bscale = z == 0 ? QSCL : 1.0f;
  bf16* C = z == 0 ? C0 : (z == 1 ? C1 : C2);
  gemm_body<64, false, false>(A, Wc + (size_t)z * NW, bias, bscale, C,
                              z == 2, M, N, K, bx, by);
}

// Output projection, bf16 A (glds path), fp32 out. Flat grid (512), swizzled.
__global__ __launch_bounds__(256) void gemm_out(
    const bf16* __restrict__ Ain, const bf16* __restrict__ W,
    const float* __restrict__ bias, float* __restrict__ Cout,
    int M, int N, int K)
{
  const int id = blockIdx.x;
  const int by = id & 63;            // same-by blocks: ids differ by 64
  const int bx = id >> 6;            // 0..7
  gemm_body<32, true, true>(Ain, W, bias, 1.0f, Cout, false, M, N, K, bx, by);
}

// ---------------------------------------------------------------------------
// Flash attention, S^T/O^T, no online max; log2-domain scores (Wq pre-scaled).
// Block = 128 q (4 waves x 32 q: two 16-q frags/wave — K/V frags and staging
// shared across frags, 2x MFMA per softmax/staging). KV tile 64, single
// buffer, register prefetch. V pre-transposed globally (Vtg[b][h][d][tok]).
// O written IN-PLACE over Q (each block reads only its own 128 Q rows in the
// prologue and writes exactly those rows at the end). Flat grid (512) with
// XCD swizzle: blocks sharing (b,h) -> same XCD for K/V L2 reuse.
// ---------------------------------------------------------------------------
__global__ __launch_bounds__(256) void attn_kernel(
    const bf16* Q, const bf16* __restrict__ Kb,
    const bf16* __restrict__ Vtg, bf16* O)
{
  __shared__ bf16 Kt[64 * 72];        // [tok][d]
  __shared__ bf16 Vt[64 * 72];        // [d][tok]
  __shared__ bf16 Ps[4 * 32 * 72];    // per-wave [q(32)][tok]

  const int tid  = threadIdx.x;
  const int wave = tid >> 6, lane = tid & 63;
  const int quad = lane >> 4, l16 = lane & 15;
  const int id = blockIdx.x;
  const int hb = id & 31;             // same (b,h) blocks: ids differ by 32
  const int h = hb & 15, b = hb >> 4;
  const int qt = id >> 5;             // 0..15
  const int qA = qt * 128 + wave * 32;
  const size_t base  = (size_t)b * S_ * DM + (size_t)h * DK;   // Q/K/O
  const size_t baseV = ((size_t)b * H_ + h) * DK * S_;         // Vtg

  // Q frags [q=l16][k=quad*8+j], pre-scaled by QSCL via the Wq cast
  bf16x8 qf[2][2];
#pragma unroll
  for (int f = 0; f < 2; ++f)
#pragma unroll
    for (int kt = 0; kt < 2; ++kt)
      qf[f][kt] = *(const bf16x8*)(Q + base + (size_t)(qA + f * 16 + l16) * DM + kt * 32 + quad * 8);

  // staging: waves 0-1 -> K rows (tok), waves 2-3 -> V^T rows (d)
  const bool kside = (wave < 2);
  const int srow  = kside ? (tid >> 1) : ((tid - 128) >> 1);   // 0..63
  const int shalf = tid & 1;
  const bf16* gp = kside
      ? (Kb + base + (size_t)srow * DM + shalf * 32)
      : (Vtg + baseV + (size_t)srow * S_ + shalf * 32);
  const size_t gstep = kside ? (size_t)64 * DM : 64;
  bf16* ldst = (kside ? Kt : Vt) + srow * 72 + shalf * 32;

  bf16x8 st[4];
#pragma unroll
  for (int c = 0; c < 4; ++c) st[c] = *(const bf16x8*)(gp + c * 8);
  gp += gstep;

  f32x4 lacc[2] = {};                  // per-frag per-lane partial sums
  f32x4 accO[2][4] = {};               // O^T[f][d=dt*16+quad*4+r][q=l16]
  bf16* Pw = Ps + wave * 32 * 72;

  constexpr int NIT = S_ / 64;
  for (int it = 0; it < NIT; ++it) {
    __syncthreads();                   // prev tile's LDS reads done
#pragma unroll
    for (int c = 0; c < 4; ++c) *(bf16x8*)(ldst + c * 8) = st[c];
    __syncthreads();                   // LDS tile ready

    if (it + 1 < NIT) {                // register prefetch of next tile
#pragma unroll
      for (int c = 0; c < 4; ++c) st[c] = *(const bf16x8*)(gp + c * 8);
      gp += gstep;
    }

    // ---- S^T: 4 tok-tiles x 2 q-frags; K frags shared across frags ----
    f32x4 sc[2][4];
#pragma unroll
    for (int ct = 0; ct < 4; ++ct) {
      const bf16* kp = Kt + (ct * 16 + l16) * 72 + quad * 8;
      const bf16x8 kf0 = *(const bf16x8*)kp;
      const bf16x8 kf1 = *(const bf16x8*)(kp + 32);
#pragma unroll
      for (int f = 0; f < 2; ++f) {
        f32x4 a = {0.f, 0.f, 0.f, 0.f};
        a = __builtin_amdgcn_mfma_f32_16x16x32_bf16(kf0, qf[f][0], a, 0, 0, 0);
        a = __builtin_amdgcn_mfma_f32_16x16x32_bf16(kf1, qf[f][1], a, 0, 0, 0);
        sc[f][ct] = a;
      }
    }

    // ---- p = exp2(sc); P^T -> per-wave LDS ----
#pragma unroll
    for (int f = 0; f < 2; ++f)
#pragma unroll
      for (int ct = 0; ct < 4; ++ct) {
        bf16x4 pk;
#pragma unroll
        for (int r = 0; r < 4; ++r) {
          const float p = fast_exp2(sc[f][ct][r]);
          lacc[f][r] += p;
          pk[r] = (bf16)p;
        }
        *(bf16x4*)(Pw + (f * 16 + l16) * 72 + ct * 16 + quad * 4) = pk;
      }

    bf16x8 pf[2][2];
#pragma unroll
    for (int f = 0; f < 2; ++f) {
      pf[f][0] = *(const bf16x8*)(Pw + (f * 16 + l16) * 72 + quad * 8);
      pf[f][1] = *(const bf16x8*)(Pw + (f * 16 + l16) * 72 + 32 + quad * 8);
    }

    // ---- O^T += V^T P; V frags shared across frags ----
#pragma unroll
    for (int dt = 0; dt < 4; ++dt) {
      const bf16* vp = Vt + (dt * 16 + l16) * 72;
      const bf16x8 vf0 = *(const bf16x8*)(vp + quad * 8);
      const bf16x8 vf1 = *(const bf16x8*)(vp + 32 + quad * 8);
#pragma unroll
      for (int f = 0; f < 2; ++f) {
        accO[f][dt] = __builtin_amdgcn_mfma_f32_16x16x32_bf16(vf0, pf[f][0], accO[f][dt], 0, 0, 0);
        accO[f][dt] = __builtin_amdgcn_mfma_f32_16x16x32_bf16(vf1, pf[f][1], accO[f][dt], 0, 0, 0);
      }
    }
  }

  // ---- epilogue: reduce l per frag, O[q][d] = O^T / l (in-lane) ----
#pragma unroll
  for (int f = 0; f < 2; ++f) {
    float l_s = (lacc[f][0] + lacc[f][1]) + (lacc[f][2] + lacc[f][3]);
    l_s += __shfl_xor(l_s, 16, 64);
    l_s += __shfl_xor(l_s, 32, 64);
    const float inv = 1.0f / l_s;
#pragma unroll
    for (int dt = 0; dt < 4; ++dt) {
      bf16x4 o;
#pragma unroll
      for (int r = 0; r < 4; ++r) o[r] = (bf16)(accO[f][dt][r] * inv);
      *(bf16x4*)(O + base + (size_t)(qA + f * 16 + l16) * DM + dt * 16 + quad * 4) = o;
    }
  }
}

// ---------------------------------------------------------------------------
extern "C" void kernel_launch(void* const* d_in, const int* in_sizes, int n_in,
                              void* d_out, int out_size, void* d_ws, size_t ws_size,
                              hipStream_t stream) {
  (void)in_sizes; (void)n_in; (void)out_size; (void)ws_size;
  const float* q  = (const float*)d_in[0];
  const float* k  = (const float*)d_in[1];
  const float* v  = (const float*)d_in[2];
  const float* Wq = (const float*)d_in[3];
  const float* bq = (const float*)d_in[4];
  const float* Wk = (const float*)d_in[5];
  const float* bk = (const float*)d_in[6];
  const float* Wv = (const float*)d_in[7];
  const float* bvv= (const float*)d_in[8];
  const float* Wo = (const float*)d_in[9];
  const float* bo = (const float*)d_in[10];
  float* out = (float*)d_out;

  // 32 MB workspace plan:
  //  [ 0, 8)  Qb (attn writes O in-place here -> Ab)
  //  [ 8,16)  Kbf
  //  [16,24)  Vtg [b][h][d][tok]
  //  [24,30)  Wc  (Wq,Wk,Wv casts)
  //  [30,32)  WoC (Wo cast)
  char* ws = (char*)d_ws;
  const size_t MB = 1024 * 1024;
  bf16* Qb  = (bf16*)(ws);
  bf16* Kbf = (bf16*)(ws + 8 * MB);
  bf16* Vtg = (bf16*)(ws + 16 * MB);
  bf16* Wc  = (bf16*)(ws + 24 * MB);
  bf16* WoC = (bf16*)(ws + 30 * MB);
  bf16* Ab  = Qb;                     // attn output, in-place over Qb

  dim3 bb(256, 1, 1);

  cast_w4<<<dim3(NW / 2048, 4, 1), bb, 0, stream>>>(Wq, Wk, Wv, Wo, Wc, WoC);

  gemm_qkv<<<dim3(768, 1, 1), bb, 0, stream>>>(
      q, k, v, Wc, bq, bk, bvv, Qb, Kbf, Vtg, M_, DM, DM);

  attn_kernel<<<dim3(512, 1, 1), bb, 0, stream>>>(Qb, Kbf, Vtg, Ab);

  gemm_out<<<dim3(512, 1, 1), bb, 0, stream>>>(Ab, WoC, bo, out, M_, DM, DM);
}